// Round 4
// baseline (238.552 us; speedup 1.0000x reference)
//
#include <hip/hip_runtime.h>

#define NROWS 500000
#define NCOLS 80
#define RPB   80                    // rows per main-kernel block
#define TPB   320                   // 16 rows x 20 chunks per slab
#define SLABS 5                     // 5 slabs x 16 rows = 80 rows
#define NBLK  (NROWS / RPB)         // 6250, exact
#define MAXBLK 256

// d_ws layout (float index)
#define WS_CNT0 0                   // uint counter, KA last-block ticket
#define WS_CNT1 1                   // uint counter, KB last-block ticket
#define WS_INVM 2                   // 1/M
#define WS_MAXP 16                  // 256 per-block maxes
#define WS_PART 512                 // 6250 per-block partials

// ---------------------------------------------------------------------------
// KA: max of iou over fg rows; last block reduces partials -> invM.
// ---------------------------------------------------------------------------
__global__ void max_kernel(const float2* __restrict__ targets, float* ws) {
    unsigned tid = blockIdx.x * blockDim.x + threadIdx.x;
    unsigned stride = gridDim.x * blockDim.x;
    float vmax = 0.0f;
    for (unsigned i = tid; i < (unsigned)NROWS; i += stride) {
        float2 t = targets[i];
        if ((int)t.x >= 1) vmax = fmaxf(vmax, t.y);
    }
    #pragma unroll
    for (int off = 32; off > 0; off >>= 1)
        vmax = fmaxf(vmax, __shfl_xor(vmax, off));
    __shared__ float red[4];
    __shared__ bool last;
    int lane = threadIdx.x & 63, wid = threadIdx.x >> 6;
    if (lane == 0) red[wid] = vmax;
    __syncthreads();
    if (threadIdx.x == 0) {
        ws[WS_MAXP + blockIdx.x] =
            fmaxf(fmaxf(red[0], red[1]), fmaxf(red[2], red[3]));
        __threadfence();
        unsigned old = atomicAdd((unsigned*)ws + WS_CNT0, 1u);
        last = (old == MAXBLK - 1);
    }
    __syncthreads();
    if (last) {
        __threadfence();
        volatile float* maxp = ws + WS_MAXP;
        float v = (threadIdx.x < MAXBLK) ? maxp[threadIdx.x] : 0.0f;
        #pragma unroll
        for (int off = 32; off > 0; off >>= 1)
            v = fmaxf(v, __shfl_xor(v, off));
        if (lane == 0) red[wid] = v;
        __syncthreads();
        if (threadIdx.x == 0) {
            float m = fmaxf(fmaxf(red[0], red[1]), fmaxf(red[2], red[3]));
            ws[WS_INVM] = 1.0f / m;
        }
    }
}

// ---------------------------------------------------------------------------
// KB: main stream. Block b owns rows [80b, 80b+80): 5 slabs of 16 rows,
// chunk address = b*1600 + s*320 + t (contiguous, coalesced). Per-chunk
// batched log: sum softplus = sum relu + log(prod(1+e_k)) -> 1 v_log per
// 4 elements. fg element corrected inline (cndmask select, no dyn index).
// Last block sums the 6250 partials -> out[0].
// ---------------------------------------------------------------------------
__global__ void __launch_bounds__(TPB)
main_kernel(const float4* __restrict__ logits4,
            const float2* __restrict__ targets,
            float* ws, float* __restrict__ out) {
    __shared__ float2 t2s[RPB];
    const unsigned t = threadIdx.x;
    const unsigned b = blockIdx.x;
    if (t < RPB) t2s[t] = targets[b * RPB + t];
    const float invM = ws[WS_INVM];
    const unsigned rl = t / 20u;             // row within slab (0..15)
    const int j0 = (int)(t - rl * 20u) * 4;  // first column of this chunk
    __syncthreads();

    float acc = 0.0f;                        // 0.75*base handled at end
    float acc_c = 0.0f;                      // fg corrections (unscaled mix)
    const unsigned base = b * (RPB * NCOLS / 4);
    #pragma unroll
    for (int s = 0; s < SLABS; ++s) {
        float4 x4 = logits4[base + (unsigned)s * TPB + t];
        float2 tt = t2s[s * 16 + rl];
        int   c = (int)tt.x - 1;
        float L = tt.y * invM;

        float e0 = __expf(-fabsf(x4.x)), e1 = __expf(-fabsf(x4.y));
        float e2 = __expf(-fabsf(x4.z)), e3 = __expf(-fabsf(x4.w));
        float a0 = 1.0f + e0, a1 = 1.0f + e1, a2 = 1.0f + e2, a3 = 1.0f + e3;
        float r0 = __builtin_amdgcn_rcpf(a0), r1 = __builtin_amdgcn_rcpf(a1);
        float r2 = __builtin_amdgcn_rcpf(a2), r3 = __builtin_amdgcn_rcpf(a3);
        float p0 = (x4.x >= 0.0f) ? r0 : 1.0f - r0;
        float p1 = (x4.y >= 0.0f) ? r1 : 1.0f - r1;
        float p2 = (x4.z >= 0.0f) ? r2 : 1.0f - r2;
        float p3 = (x4.w >= 0.0f) ? r3 : 1.0f - r3;
        float u0 = fmaxf(x4.x, 0.0f), u1 = fmaxf(x4.y, 0.0f);
        float u2 = fmaxf(x4.z, 0.0f), u3 = fmaxf(x4.w, 0.0f);
        // sum softplus - sum sigmoid over the chunk
        acc += (u0 + u1) + (u2 + u3) + __logf((a0 * a1) * (a2 * a3))
             - ((p0 + p1) + (p2 + p3));

        int d = c - j0;
        if ((unsigned)d < 4u) {              // this chunk holds the fg elem
            float xc = x4.x, ec = e0, pc = p0, uc = u0;
            if (d == 1) { xc = x4.y; ec = e1; pc = p1; uc = u1; }
            if (d == 2) { xc = x4.z; ec = e2; pc = p2; uc = u2; }
            if (d == 3) { xc = x4.w; ec = e3; pc = p3; uc = u3; }
            float spc = uc + __logf(1.0f + ec);
            float full;
            if (pc <= L) {
                float spn = spc - xc;        // softplus(-x)
                full = 0.25f * (spn * L + (pc - L));
            } else {
                full = 0.75f * (spc * (1.0f - L) + (L - pc));
            }
            acc_c += full - 0.75f * (spc - pc);
        }
    }
    acc = 0.75f * acc + acc_c;
    #pragma unroll
    for (int off = 32; off > 0; off >>= 1)
        acc += __shfl_xor(acc, off);
    __shared__ float red[TPB / 64];
    __shared__ bool last;
    int lane = threadIdx.x & 63, wid = threadIdx.x >> 6;
    if (lane == 0) red[wid] = acc;
    __syncthreads();
    if (threadIdx.x == 0) {
        float s = 0.0f;
        #pragma unroll
        for (int w = 0; w < TPB / 64; ++w) s += red[w];
        ws[WS_PART + b] = s;
        __threadfence();
        unsigned old = atomicAdd((unsigned*)ws + WS_CNT1, 1u);
        last = (old == NBLK - 1);
    }
    __syncthreads();
    if (last) {
        __threadfence();
        volatile float* part = ws + WS_PART;
        float a = 0.0f;
        for (unsigned i = t; i < (unsigned)NBLK; i += TPB) a += part[i];
        #pragma unroll
        for (int off = 32; off > 0; off >>= 1)
            a += __shfl_xor(a, off);
        if (lane == 0) red[wid] = a;
        __syncthreads();
        if (threadIdx.x == 0) {
            float s = 0.0f;
            #pragma unroll
            for (int w = 0; w < TPB / 64; ++w) s += red[w];
            out[0] = s;
        }
    }
}

extern "C" void kernel_launch(void* const* d_in, const int* in_sizes, int n_in,
                              void* d_out, int out_size, void* d_ws, size_t ws_size,
                              hipStream_t stream) {
    const float* logits  = (const float*)d_in[0];   // (N, C) f32
    const float* targets = (const float*)d_in[1];   // (N, 2) f32
    float* out = (float*)d_out;
    float* ws  = (float*)d_ws;

    hipMemsetAsync(ws, 0, 8, stream);               // reset the two tickets
    max_kernel <<<MAXBLK, 256, 0, stream>>>((const float2*)targets, ws);
    main_kernel<<<NBLK,  TPB, 0, stream>>>((const float4*)logits,
                                           (const float2*)targets, ws, out);
}

// Round 5
// 47.327 us; speedup vs baseline: 5.0405x; 5.0405x over previous
//
#include <hip/hip_runtime.h>

#define NROWS 500000
#define NCOLS 80
#define NV (NROWS * NCOLS / 4)     // 10,000,000 float4 chunks

#define K1_BLOCKS 1250
#define K1_TPB    320
#define K1_THREADS (K1_BLOCKS * K1_TPB)   // 400,000
#define K1_ITERS  25                      // 400,000 * 25 = NV exactly

#define K2_BLOCKS 256
#define K2_TPB    256

// d_ws float layout (all written-before-read every call; no memsets needed)
#define WS_MAXP 0        // [0 .. 1250)      per-block max from K1
#define WS_SUM1 2048     // [2048 .. 3298)   per-block base sums from K1
#define WS_SUM2 4096     // [4096 .. 4352)   per-block correction sums from K2

// ---------------------------------------------------------------------------
// K1: fused (a) max iou over fg rows, (b) sum of 0.75*(softplus(x)-sigmoid(x))
// over all 40M logits. Batched log: per float4, sum softplus =
// sum(max(x,0)) + log(prod(1+e_k)), one v_log per 4 elements.
// Fence-free: per-block partials to ws.
// ---------------------------------------------------------------------------
__global__ void __launch_bounds__(K1_TPB)
stream_kernel(const float4* __restrict__ logits4,
              const float2* __restrict__ targets,
              float* __restrict__ maxp, float* __restrict__ sump) {
    const unsigned tid = blockIdx.x * K1_TPB + threadIdx.x;

    // --- max scan of targets (2 coalesced float2 rounds) ---
    float vmax = 0.0f;
    {
        float2 t0 = targets[tid];                       // tid < 400000 < NROWS
        if ((int)t0.x >= 1) vmax = t0.y;
        unsigned i2 = tid + K1_THREADS;
        if (i2 < (unsigned)NROWS) {
            float2 t1 = targets[i2];
            if ((int)t1.x >= 1) vmax = fmaxf(vmax, t1.y);
        }
    }

    // --- base stream ---
    float acc = 0.0f;
    #pragma unroll 5
    for (int i = 0; i < K1_ITERS; ++i) {
        float4 x4 = logits4[tid + (unsigned)i * K1_THREADS];
        float e0 = __expf(-fabsf(x4.x)), e1 = __expf(-fabsf(x4.y));
        float e2 = __expf(-fabsf(x4.z)), e3 = __expf(-fabsf(x4.w));
        float a0 = 1.0f + e0, a1 = 1.0f + e1;
        float a2 = 1.0f + e2, a3 = 1.0f + e3;
        float r0 = __builtin_amdgcn_rcpf(a0), r1 = __builtin_amdgcn_rcpf(a1);
        float r2 = __builtin_amdgcn_rcpf(a2), r3 = __builtin_amdgcn_rcpf(a3);
        float p0 = (x4.x >= 0.0f) ? r0 : 1.0f - r0;
        float p1 = (x4.y >= 0.0f) ? r1 : 1.0f - r1;
        float p2 = (x4.z >= 0.0f) ? r2 : 1.0f - r2;
        float p3 = (x4.w >= 0.0f) ? r3 : 1.0f - r3;
        float u  = (fmaxf(x4.x, 0.0f) + fmaxf(x4.y, 0.0f))
                 + (fmaxf(x4.z, 0.0f) + fmaxf(x4.w, 0.0f));
        acc += u + __logf((a0 * a1) * (a2 * a3))
                 - ((p0 + p1) + (p2 + p3));
    }

    // --- dual reduce (sum, max) ---
    #pragma unroll
    for (int off = 32; off > 0; off >>= 1) {
        acc  += __shfl_xor(acc, off);
        vmax  = fmaxf(vmax, __shfl_xor(vmax, off));
    }
    __shared__ float reds[K1_TPB / 64], redm[K1_TPB / 64];
    int lane = threadIdx.x & 63, wid = threadIdx.x >> 6;
    if (lane == 0) { reds[wid] = acc; redm[wid] = vmax; }
    __syncthreads();
    if (threadIdx.x == 0) {
        float s = 0.0f, m = 0.0f;
        #pragma unroll
        for (int w = 0; w < K1_TPB / 64; ++w) {
            s += reds[w];
            m  = fmaxf(m, redm[w]);
        }
        sump[blockIdx.x] = 0.75f * s;
        maxp[blockIdx.x] = m;
    }
}

// ---------------------------------------------------------------------------
// K2: M from the 1250 block maxes, then per-fg-row correction:
//   add  full_term(x_c, L) - 0.75*(softplus(x_c) - sigmoid(x_c))
// x_c gathered from logits (L3-resident after K1).
// ---------------------------------------------------------------------------
__global__ void __launch_bounds__(K2_TPB)
correction_kernel(const float* __restrict__ logits,
                  const float2* __restrict__ targets,
                  const float* __restrict__ maxp,
                  float* __restrict__ sump2) {
    __shared__ float red[K2_TPB / 64];
    __shared__ float sM;
    int lane = threadIdx.x & 63, wid = threadIdx.x >> 6;

    // all blocks redundantly reduce the 1250 maxes (5 KB, L2-hot)
    float m = 0.0f;
    for (unsigned i = threadIdx.x; i < (unsigned)K1_BLOCKS; i += K2_TPB)
        m = fmaxf(m, maxp[i]);
    #pragma unroll
    for (int off = 32; off > 0; off >>= 1)
        m = fmaxf(m, __shfl_xor(m, off));
    if (lane == 0) red[wid] = m;
    __syncthreads();
    if (threadIdx.x == 0) {
        float mm = 0.0f;
        #pragma unroll
        for (int w = 0; w < K2_TPB / 64; ++w) mm = fmaxf(mm, red[w]);
        sM = mm;
    }
    __syncthreads();
    const float invM = __builtin_amdgcn_rcpf(sM);

    float acc = 0.0f;
    const unsigned stride = K2_BLOCKS * K2_TPB;     // 65536
    for (unsigned r = blockIdx.x * K2_TPB + threadIdx.x;
         r < (unsigned)NROWS; r += stride) {
        float2 t = targets[r];
        int c = (int)t.x - 1;
        if (c >= 0) {
            float x  = logits[r * (unsigned)NCOLS + (unsigned)c];
            float L  = t.y * invM;
            float e  = __expf(-fabsf(x));
            float a  = 1.0f + e;
            float rr = __builtin_amdgcn_rcpf(a);
            float p  = (x >= 0.0f) ? rr : 1.0f - rr;
            float sp = fmaxf(x, 0.0f) + __logf(a);
            float full;
            if (p <= L) {
                float spn = sp - x;                   // softplus(-x)
                full = 0.25f * (spn * L + (p - L));
            } else {
                full = 0.75f * (sp * (1.0f - L) + (L - p));
            }
            acc += full - 0.75f * (sp - p);
        }
    }
    #pragma unroll
    for (int off = 32; off > 0; off >>= 1)
        acc += __shfl_xor(acc, off);
    __syncthreads();                                  // red[] reuse
    if (lane == 0) red[wid] = acc;
    __syncthreads();
    if (threadIdx.x == 0) {
        float s = 0.0f;
        #pragma unroll
        for (int w = 0; w < K2_TPB / 64; ++w) s += red[w];
        sump2[blockIdx.x] = s;
    }
}

// ---------------------------------------------------------------------------
// K3: single block sums 1250 + 256 partials -> out[0]
// ---------------------------------------------------------------------------
__global__ void final_kernel(const float* __restrict__ sump,
                             const float* __restrict__ sump2,
                             float* __restrict__ out) {
    float acc = 0.0f;
    for (unsigned i = threadIdx.x; i < (unsigned)K1_BLOCKS; i += 256u)
        acc += sump[i];
    if (threadIdx.x < K2_BLOCKS) acc += sump2[threadIdx.x];
    #pragma unroll
    for (int off = 32; off > 0; off >>= 1)
        acc += __shfl_xor(acc, off);
    __shared__ float red[4];
    int lane = threadIdx.x & 63, wid = threadIdx.x >> 6;
    if (lane == 0) red[wid] = acc;
    __syncthreads();
    if (threadIdx.x == 0)
        out[0] = (red[0] + red[1]) + (red[2] + red[3]);
}

extern "C" void kernel_launch(void* const* d_in, const int* in_sizes, int n_in,
                              void* d_out, int out_size, void* d_ws, size_t ws_size,
                              hipStream_t stream) {
    const float* logits  = (const float*)d_in[0];   // (N, C) f32
    const float* targets = (const float*)d_in[1];   // (N, 2) f32
    float* out = (float*)d_out;
    float* ws  = (float*)d_ws;

    stream_kernel<<<K1_BLOCKS, K1_TPB, 0, stream>>>(
        (const float4*)logits, (const float2*)targets,
        ws + WS_MAXP, ws + WS_SUM1);
    correction_kernel<<<K2_BLOCKS, K2_TPB, 0, stream>>>(
        logits, (const float2*)targets, ws + WS_MAXP, ws + WS_SUM2);
    final_kernel<<<1, 256, 0, stream>>>(ws + WS_SUM1, ws + WS_SUM2, out);
}